// Round 18
// baseline (314.396 us; speedup 1.0000x reference)
//
#include <hip/hip_runtime.h>
#include <cstdint>
#include <cmath>

#define S_LEN 2048
#define D_DIM 1024
#define NH    16
#define DKD   64
#define BATCH 4
#define M_TOT (BATCH * S_LEN)   // 8192

// 0.125 * log2(e): folded into Q so QK^T lands directly in exp2 domain
#define QSCALE 0.18033688011112042f

typedef __attribute__((ext_vector_type(8)))  short bf16x8;
typedef __attribute__((ext_vector_type(4)))  float f32x4;
typedef __attribute__((ext_vector_type(16))) float f32x16;

typedef __attribute__((address_space(1))) void as1_void;
typedef __attribute__((address_space(3))) void as3_void;

__device__ __forceinline__ short f2b(float f) {
    union { float f; uint32_t u; } v; v.f = f;
    uint32_t r = v.u + 0x7fffu + ((v.u >> 16) & 1u);   // RNE
    return (short)(r >> 16);
}

__device__ __forceinline__ void gld_lds16(const void* g, void* l) {
    __builtin_amdgcn_global_load_lds((as1_void*)g, (as3_void*)l, 16, 0, 0);
}

__device__ __forceinline__ float fast_exp2(float x) {
#if __has_builtin(__builtin_amdgcn_exp2f)
    return __builtin_amdgcn_exp2f(x);
#else
    return exp2f(x);
#endif
}

__device__ __forceinline__ uint32_t cvtpk(float lo, float hi) {
    uint32_t r;
    asm("v_cvt_pk_bf16_f32 %0, %1, %2" : "=v"(r) : "v"(lo), "v"(hi));
    return r;
}

// two genuinely-distinct values: validated by R2 (T12 packing)
__device__ __forceinline__ void pl32swap(uint32_t& a, uint32_t& b) {
    asm volatile("v_permlane32_swap_b32 %0, %1" : "+v"(a), "+v"(b));
}

// ---------------- fused prep: x-cast | weight transpose+cast | RoPE table ---------
__global__ __launch_bounds__(256) void prep_k(const float* __restrict__ x,
                                              short* __restrict__ xb,
                                              const float* __restrict__ w0,
                                              const float* __restrict__ w1,
                                              const float* __restrict__ w2,
                                              const float* __restrict__ w3,
                                              short* __restrict__ o0,
                                              short* __restrict__ o1,
                                              short* __restrict__ o2,
                                              short* __restrict__ o3,
                                              float* __restrict__ ct,
                                              float* __restrict__ st) {
    __shared__ float tile[32][33];
    const int bid = blockIdx.x;
    const int t   = threadIdx.x;

    if (bid < 4096) {
        size_t i = (size_t)bid * 256 + t;
        const float4* p = (const float4*)x + i * 2;
        float4 a = p[0], b = p[1];
        bf16x8 o;
        o[0]=f2b(a.x); o[1]=f2b(a.y); o[2]=f2b(a.z); o[3]=f2b(a.w);
        o[4]=f2b(b.x); o[5]=f2b(b.y); o[6]=f2b(b.z); o[7]=f2b(b.w);
        *((bf16x8*)xb + i) = o;
    } else if (bid < 8192) {
        const int wid = bid - 4096;
        const int z   = wid >> 10;          // 0..3
        const int t2  = wid & 1023;
        const int bx  = (t2 & 31) * 32;
        const int by  = (t2 >> 5) * 32;
        const float* src = z == 0 ? w0 : z == 1 ? w1 : z == 2 ? w2 : w3;
        short*       dst = z == 0 ? o0 : z == 1 ? o1 : z == 2 ? o2 : o3;
        const int tx = t & 31, ty = t >> 5;  // 32 x 8
        #pragma unroll
        for (int i = 0; i < 4; ++i)
            tile[ty * 4 + i][tx] = src[(size_t)(by + ty * 4 + i) * D_DIM + bx + tx];
        __syncthreads();
        #pragma unroll
        for (int i = 0; i < 4; ++i)
            dst[(size_t)(bx + ty * 4 + i) * D_DIM + by + tx] = f2b(tile[tx][ty * 4 + i]);
    } else {
        int i = (bid - 8192) * 256 + t;      // 2048*32 = 65536
        int s = i >> 5, tt = i & 31;
        float inv = (float)pow(10000.0, -(double)(2 * tt) / 64.0);
        float ang = (float)s * inv;
        float sn, cs;
        sincosf(ang, &sn, &cs);
        ct[i] = cs; st[i] = sn;
    }
}

// ---------------- merged QKV GEMM (z = 0:Q, 1:K, 2:V) — R17 verbatim ----------------
__global__ __launch_bounds__(256, 4) void gemm_qkv_k(const short* __restrict__ A,
                                                     const short* __restrict__ Wt3,
                                                     short* __restrict__ Qb,
                                                     short* __restrict__ Kb,
                                                     short* __restrict__ Vt,
                                                     const float* __restrict__ ctab,
                                                     const float* __restrict__ stab) {
    const int K = 1024;
    __shared__ __align__(16) short smem[2 * 128 * 64];   // As|Bs; reused for C-stage
    short* As = smem;
    short* Bs = smem + 128 * 64;

    const int z = blockIdx.z;
    const short* BT = Wt3 + (size_t)z * D_DIM * D_DIM;

    const int l = blockIdx.y * 8 + blockIdx.x;   // 0..511
    const int mbase = ((l & 7) * 8 + (l >> 6)) * 128;
    const int nbase = ((l >> 3) & 7) * 128;

    const int t = threadIdx.x;
    const int lane = t & 63;
    const int li = lane & 15;
    const int g  = lane >> 4;
    const int w  = t >> 6;
    const int wr = w >> 1, wc = w & 1;

    f32x4 acc[4][4] = {};

    for (int kt = 0; kt < K / 64; ++kt) {
        const int k0 = kt * 64;
        #pragma unroll
        for (int it = 0; it < 4; ++it) {
            int idx = it * 256 + t;
            int r = idx >> 3, p = idx & 7;
            int c = p ^ (r & 7);
            gld_lds16(A + (size_t)(mbase + r) * K + k0 + c * 8, &As[idx * 8]);
        }
        #pragma unroll
        for (int it = 0; it < 4; ++it) {
            int idx = it * 256 + t;
            int r = idx >> 3, p = idx & 7;
            int c = p ^ (r & 7);
            gld_lds16(BT + (size_t)(nbase + r) * K + k0 + c * 8, &Bs[idx * 8]);
        }
        __syncthreads();

        #pragma unroll
        for (int kk = 0; kk < 2; ++kk) {
            bf16x8 af[4], bfr[4];
            #pragma unroll
            for (int mt = 0; mt < 4; ++mt) {
                int row = wr * 64 + mt * 16 + li;
                int c = (kk * 4 + g) ^ (row & 7);
                af[mt] = *(const bf16x8*)&As[row * 64 + c * 8];
            }
            #pragma unroll
            for (int nt = 0; nt < 4; ++nt) {
                int row = wc * 64 + nt * 16 + li;
                int c = (kk * 4 + g) ^ (row & 7);
                bfr[nt] = *(const bf16x8*)&Bs[row * 64 + c * 8];
            }
            #pragma unroll
            for (int mt = 0; mt < 4; ++mt)
                #pragma unroll
                for (int nt = 0; nt < 4; ++nt)
                    acc[mt][nt] = __builtin_amdgcn_mfma_f32_16x16x32_bf16(
                        af[mt], bfr[nt], acc[mt][nt], 0, 0, 0);
        }
        __syncthreads();
    }

    if (z == 2) {
        // V: stage C^T tile into smem [nloc][mloc] (chunk-XOR), then coalesced rows
        #pragma unroll
        for (int mt = 0; mt < 4; ++mt) {
            #pragma unroll
            for (int nt = 0; nt < 4; ++nt) {
                const int nloc = wc * 64 + nt * 16 + li;
                #pragma unroll
                for (int j = 0; j < 4; ++j) {
                    const int mloc = wr * 64 + mt * 16 + g * 4 + j;
                    smem[nloc * 128 + (((mloc >> 3) ^ (nloc & 7)) << 3) + (mloc & 7)] =
                        f2b(acc[mt][nt][j]);
                }
            }
        }
        __syncthreads();
        const int b = mbase >> 11, s2 = mbase & (S_LEN - 1);
        #pragma unroll
        for (int rr = 0; rr < 8; ++rr) {
            const int row = w * 32 + rr * 4 + (lane >> 4);   // nloc
            const int mc  = lane & 15;
            const int phys = mc ^ (row & 7);
            bf16x8 vrow = *(const bf16x8*)&smem[row * 128 + phys * 8];
            const int n = nbase + row;
            const int h = n >> 6, dk = n & 63;
            *(bf16x8*)&Vt[((size_t)((b * NH + h) * DKD + dk)) * S_LEN + s2 + mc * 8] = vrow;
        }
    } else {
        // Q/K: RoPE in-register, stage C [mloc][nloc] chunk-XOR, coalesced stores
        short* Out = (z == 0) ? Qb : Kb;
        const int s2b = mbase & (S_LEN - 1);
        #pragma unroll
        for (int mt = 0; mt < 4; ++mt) {
            #pragma unroll
            for (int nt = 0; nt < 4; ++nt) {
                const int nloc = wc * 64 + nt * 16 + li;
                const int tt = (nloc & 63) >> 1;
                #pragma unroll
                for (int j = 0; j < 4; ++j) {
                    const int mloc = wr * 64 + mt * 16 + g * 4 + j;
                    const int s2 = s2b + mloc;
                    float v = acc[mt][nt][j];
                    float pv = __shfl_xor(v, 1);
                    float cs = ctab[s2 * 32 + tt];
                    float sn = stab[s2 * 32 + tt];
                    float o = (nloc & 1) ? (pv * sn + v * cs) : (v * cs - pv * sn);
                    if (z == 0) o *= QSCALE;
                    smem[mloc * 128 + (((nloc >> 3) ^ (mloc & 7)) << 3) + (nloc & 7)] = f2b(o);
                }
            }
        }
        __syncthreads();
        const int b = mbase >> 11;
        const int seg = lane >> 3, pos = lane & 7;
        const int half = seg & 1;
        const int h = (nbase >> 6) + half;
        #pragma unroll
        for (int rr = 0; rr < 8; ++rr) {
            const int rloc = w * 32 + rr * 4 + (seg >> 1);
            const int chunk = half * 8 + pos;
            bf16x8 vrow = *(const bf16x8*)&smem[rloc * 128 + ((chunk ^ (rloc & 7)) << 3)];
            *(bf16x8*)&Out[((size_t)((b * NH + h) * S_LEN + s2b + rloc)) * DKD + pos * 8] = vrow;
        }
    }
}

// ---------------- output GEMM: out[M][1024] fp32, XCD-owns-A; VGPR cap 128 --------
__global__ __launch_bounds__(256, 4) void gemm_out_k(const short* __restrict__ A,
                                                     const short* __restrict__ BT,
                                                     float* __restrict__ Cout) {
    const int K = 1024;
    __shared__ short As[128 * 64];
    __shared__ short Bs[128 * 64];

    const int l = blockIdx.y * 8 + blockIdx.x;   // 0..511
    const int mbase = ((l & 7) * 8 + (l >> 6)) * 128;
    const int nbase = ((l >> 3) & 7) * 128;

    const int t = threadIdx.x;
    const int lane = t & 63;
    const int li = lane & 15;
    const int g  = lane >> 4;
    const int w  = t >> 6;
    const int wr = w >> 1, wc = w & 1;

    f32x4 acc[4][4] = {};

    for (int kt = 0; kt < K / 64; ++kt) {
        const int k0 = kt * 64;
        #pragma unroll
        for (int it = 0; it < 4; ++it) {
            int idx = it * 256 + t;
            int r = idx >> 3, p = idx & 7;
            int c = p ^ (r & 7);
            gld_lds16(A + (size_t)(mbase + r) * K + k0 + c * 8, &As[idx * 8]);
        }
        #pragma unroll
        for (int it = 0; it < 4; ++it) {
            int idx = it * 256 + t;
            int r = idx >> 3, p = idx & 7;
            int c = p ^ (r & 7);
            gld_lds16(BT + (size_t)(nbase + r) * K + k0 + c * 8, &Bs[idx * 8]);
        }
        __syncthreads();

        #pragma unroll
        for (int kk = 0; kk < 2; ++kk) {
            bf16x8 af[4], bfr[4];
            #pragma unroll
            for (int mt = 0; mt < 4; ++mt) {
                int row = wr * 64 + mt * 16 + li;
                int c = (kk * 4 + g) ^ (row & 7);
                af[mt] = *(const bf16x8*)&As[row * 64 + c * 8];
            }
            #pragma unroll
            for (int nt = 0; nt < 4; ++nt) {
                int row = wc * 64 + nt * 16 + li;
                int c = (kk * 4 + g) ^ (row & 7);
                bfr[nt] = *(const bf16x8*)&Bs[row * 64 + c * 8];
            }
            #pragma unroll
            for (int mt = 0; mt < 4; ++mt)
                #pragma unroll
                for (int nt = 0; nt < 4; ++nt)
                    acc[mt][nt] = __builtin_amdgcn_mfma_f32_16x16x32_bf16(
                        af[mt], bfr[nt], acc[mt][nt], 0, 0, 0);
        }
        __syncthreads();
    }

    #pragma unroll
    for (int mt = 0; mt < 4; ++mt)
        #pragma unroll
        for (int nt = 0; nt < 4; ++nt) {
            const int n = nbase + wc * 64 + nt * 16 + li;
            #pragma unroll
            for (int j = 0; j < 4; ++j) {
                const int m = mbase + wr * 64 + mt * 16 + g * 4 + j;
                Cout[(size_t)m * D_DIM + n] = acc[mt][nt][j];
            }
        }
}

// ---------------- flash attention, swapped-QK 32x32, no max ----------------
// R17 + (a) per-half lsum partial, single cross-half shfl in epilogue (assoc.);
// (b) V fragments hoisted into registers before exp2/pack (overlap LDS latency
// with softmax VALU; +32 VGPR, still under the 128 cap).
__global__ __launch_bounds__(256, 4) void attn_k(const short* __restrict__ Qb,
                                                 const short* __restrict__ Kb,
                                                 const short* __restrict__ Vt,
                                                 short* __restrict__ Ao) {
    __shared__ short Ks[2][64 * 64];
    __shared__ short Vs[2][64 * 64];

    const int braw = blockIdx.y * 16 + blockIdx.x;   // nwg=1024
    const int tile = (braw & 7) * 128 + (braw >> 3);
    const int bxs = tile & 15, bh = tile >> 4;       // blocks sharing bh -> same XCD

    const int t = threadIdx.x;
    const int lane = t & 63;
    const int ql = lane & 31;
    const int hi = lane >> 5;
    const int w  = t >> 6;
    const int q0 = bxs * 128;

    // Q fragments (B-operand): lane holds Q[q=ql][k = kb*16 + hi*8 + i]
    bf16x8 aq[4];
    {
        const short* qp = Qb + ((size_t)bh * S_LEN + q0 + w * 32 + ql) * DKD;
        #pragma unroll
        for (int kb = 0; kb < 4; ++kb)
            aq[kb] = *(const bf16x8*)(qp + kb * 16 + hi * 8);
    }

    f32x16 oacc[2] = {};
    float lsum = 0.f;   // per-half partial; cross-half combine deferred to epilogue

    auto stageKV = [&](int bb, int kt) {
        const int kb = kt * 64;
        #pragma unroll
        for (int it = 0; it < 2; ++it) {
            int idx = it * 256 + t;
            int r = idx >> 3, p = idx & 7;
            int c = p ^ (r & 7);
            gld_lds16(Kb + ((size_t)bh * S_LEN + kb + r) * DKD + c * 8, &Ks[bb][idx * 8]);
        }
        #pragma unroll
        for (int it = 0; it < 2; ++it) {
            int idx = it * 256 + t;
            int r = idx >> 3, p = idx & 7;
            int c = p ^ (r & 7);
            gld_lds16(Vt + ((size_t)bh * DKD + r) * S_LEN + kb + c * 8, &Vs[bb][idx * 8]);
        }
    };

    stageKV(0, 0);
    int buf = 0;
    for (int kt = 0; kt < S_LEN / 64; ++kt) {
        __syncthreads();                                   // staged tile ready
        if (kt + 1 < S_LEN / 64) stageKV(buf ^ 1, kt + 1); // prefetch next

        const short* KsB = Ks[buf];
        const short* VsB = Vs[buf];

        // S^T = K·Q^T   (already in exp2 domain via QSCALE)
        f32x16 s0 = {}, s1 = {};
        #pragma unroll
        for (int kb = 0; kb < 4; ++kb) {
            const int ch = ((kb * 2 + hi) ^ (ql & 7)) * 8;
            bf16x8 k0 = *(const bf16x8*)&KsB[ql * 64 + ch];
            bf16x8 k1 = *(const bf16x8*)&KsB[(ql + 32) * 64 + ch];
            s0 = __builtin_amdgcn_mfma_f32_32x32x16_bf16(k0, aq[kb], s0, 0, 0, 0);
            s1 = __builtin_amdgcn_mfma_f32_32x32x16_bf16(k1, aq[kb], s1, 0, 0, 0);
        }

        // hoist V fragments now: LDS-read latency overlaps the exp2/pack VALU below
        bf16x8 vf0[4], vf1[4];
        #pragma unroll
        for (int kb = 0; kb < 4; ++kb) {
            const int ch = ((kb * 2 + hi) ^ (ql & 7)) * 8;
            vf0[kb] = *(const bf16x8*)&VsB[ql * 64 + ch];
            vf1[kb] = *(const bf16x8*)&VsB[(32 + ql) * 64 + ch];
        }

        // P = exp2(S) directly (no max subtraction); accumulate per-half row sum
        float rs0 = 0.f, rs1 = 0.f;
        #pragma unroll
        for (int r = 0; r < 16; ++r) {
            s0[r] = fast_exp2(s0[r]); rs0 += s0[r];
            s1[r] = fast_exp2(s1[r]); rs1 += s1[r];
        }
        lsum += rs0 + rs1;

        // pack P into PV B-fragments: cvt_pk pairs + permlane32_swap (T12)
        bf16x8 pb[4];
        #pragma unroll
        for (int kb2 = 0; kb2 < 2; ++kb2) {
            uint32_t A0 = cvtpk(s0[kb2 * 8 + 0], s0[kb2 * 8 + 1]);
            uint32_t A1 = cvtpk(s0[kb2 * 8 + 2], s0[kb2 * 8 + 3]);
            uint32_t A2 = cvtpk(s0[kb2 * 8 + 4], s0[kb2 * 8 + 5]);
            uint32_t A3 = cvtpk(s0[kb2 * 8 + 6], s0[kb2 * 8 + 7]);
            pl32swap(A0, A2); pl32swap(A1, A3);
            union { uint32_t u[4]; bf16x8 v; } pk;
            pk.u[0] = A0; pk.u[1] = A1; pk.u[2] = A2; pk.u[3] = A3;
            pb[kb2] = pk.v;

            uint32_t B0 = cvtpk(s1[kb2 * 8 + 0], s1[kb2 * 8 + 1]);
            uint32_t B1 = cvtpk(s1[kb2 * 8 + 2], s1[kb2 * 8 + 3]);
            uint32_t B2 = cvtpk(s1[kb2 * 8 + 4], s1[kb2 * 8 + 5]);
            uint32_t B3 = cvtpk(s1[kb2 * 8 + 6], s1[kb2 * 8 + 7]);
            pl32swap(B0, B2); pl32swap(B1, B3);
            union { uint32_t u[4]; bf16x8 v; } pk2;
            pk2.u[0] = B0; pk2.u[1] = B1; pk2.u[2] = B2; pk2.u[3] = B3;
            pb[2 + kb2] = pk2.v;
        }

        // O^T += V^T · P^T  (V already in registers)
        #pragma unroll
        for (int kb = 0; kb < 4; ++kb) {
            oacc[0] = __builtin_amdgcn_mfma_f32_32x32x16_bf16(vf0[kb], pb[kb], oacc[0], 0, 0, 0);
            oacc[1] = __builtin_amdgcn_mfma_f32_32x32x16_bf16(vf1[kb], pb[kb], oacc[1], 0, 0, 0);
        }
        buf ^= 1;
    }

    // epilogue: one cross-half combine for the whole loop (associativity)
    lsum += __shfl_xor(lsum, 32);
    const float inv = 1.0f / lsum;
    const int b = bh >> 4, h = bh & 15;
    short* op = Ao + ((size_t)(b * S_LEN + q0 + w * 32 + ql)) * D_DIM + h * DKD;
    #pragma unroll
    for (int ds = 0; ds < 2; ++ds)
        #pragma unroll
        for (int r4 = 0; r4 < 4; ++r4) {
            uint2 pk;
            pk.x = cvtpk(oacc[ds][r4 * 4 + 0] * inv, oacc[ds][r4 * 4 + 1] * inv);
            pk.y = cvtpk(oacc[ds][r4 * 4 + 2] * inv, oacc[ds][r4 * 4 + 3] * inv);
            *(uint2*)(op + ds * 32 + r4 * 8 + hi * 4) = pk;
        }
}

// ---------------- launch ----------------
extern "C" void kernel_launch(void* const* d_in, const int* in_sizes, int n_in,
                              void* d_out, int out_size, void* d_ws, size_t ws_size,
                              hipStream_t stream) {
    const float* x  = (const float*)d_in[0];
    const float* Wq = (const float*)d_in[2];
    const float* Wk = (const float*)d_in[3];
    const float* Wv = (const float*)d_in[4];
    const float* Wo = (const float*)d_in[5];

    char* ws = (char*)d_ws;
    short* xb  = (short*)(ws);                         // 16 MB
    short* Wqt = (short*)(ws + (size_t)(16 << 20));    // 2 MB each; Wq/Wk/Wv contiguous
    short* Wkt = (short*)(ws + (size_t)(18 << 20));
    short* Wvt = (short*)(ws + (size_t)(20 << 20));
    short* Wot = (short*)(ws + (size_t)(22 << 20));
    short* Qb  = (short*)(ws + (size_t)(24 << 20));    // 16 MB [BH][S][DK]
    short* Kb  = (short*)(ws + (size_t)(40 << 20));    // 16 MB
    short* Vt  = (short*)(ws + (size_t)(56 << 20));    // 16 MB [BH][DK][S]
    short* Ao  = (short*)(ws + (size_t)(72 << 20));    // 16 MB [B][S][D]
    float* ctab = (float*)(ws + (size_t)(88 << 20));   // 256 KB
    float* stab = (float*)(ws + (size_t)(88 << 20) + (1 << 18));

    prep_k<<<8448, 256, 0, stream>>>(x, xb, Wq, Wk, Wv, Wo, Wqt, Wkt, Wvt, Wot, ctab, stab);

    gemm_qkv_k<<<dim3(8, 64, 3), 256, 0, stream>>>(xb, Wqt, Qb, Kb, Vt, ctab, stab);

    attn_k<<<dim3(16, 64), 256, 0, stream>>>(Qb, Kb, Vt, Ao);

    gemm_out_k<<<dim3(8, 64), 256, 0, stream>>>(Ao, Wot, (float*)d_out);
}

// Round 19
// 184.845 us; speedup vs baseline: 1.7009x; 1.7009x over previous
//
#include <hip/hip_runtime.h>
#include <cstdint>
#include <cmath>

#define S_LEN 2048
#define D_DIM 1024
#define NH    16
#define DKD   64
#define BATCH 4
#define M_TOT (BATCH * S_LEN)   // 8192

// 0.125 * log2(e): folded into Q so QK^T lands directly in exp2 domain
#define QSCALE 0.18033688011112042f

typedef __attribute__((ext_vector_type(8)))  short bf16x8;
typedef __attribute__((ext_vector_type(4)))  float f32x4;
typedef __attribute__((ext_vector_type(16))) float f32x16;

typedef __attribute__((address_space(1))) void as1_void;
typedef __attribute__((address_space(3))) void as3_void;

__device__ __forceinline__ short f2b(float f) {
    union { float f; uint32_t u; } v; v.f = f;
    uint32_t r = v.u + 0x7fffu + ((v.u >> 16) & 1u);   // RNE
    return (short)(r >> 16);
}

__device__ __forceinline__ void gld_lds16(const void* g, void* l) {
    __builtin_amdgcn_global_load_lds((as1_void*)g, (as3_void*)l, 16, 0, 0);
}

__device__ __forceinline__ float fast_exp2(float x) {
#if __has_builtin(__builtin_amdgcn_exp2f)
    return __builtin_amdgcn_exp2f(x);
#else
    return exp2f(x);
#endif
}

__device__ __forceinline__ uint32_t cvtpk(float lo, float hi) {
    uint32_t r;
    asm("v_cvt_pk_bf16_f32 %0, %1, %2" : "=v"(r) : "v"(lo), "v"(hi));
    return r;
}

// two genuinely-distinct values: validated by R2 (T12 packing)
__device__ __forceinline__ void pl32swap(uint32_t& a, uint32_t& b) {
    asm volatile("v_permlane32_swap_b32 %0, %1" : "+v"(a), "+v"(b));
}

// ---------------- fused prep: x-cast | weight transpose+cast | RoPE table ---------
__global__ __launch_bounds__(256) void prep_k(const float* __restrict__ x,
                                              short* __restrict__ xb,
                                              const float* __restrict__ w0,
                                              const float* __restrict__ w1,
                                              const float* __restrict__ w2,
                                              const float* __restrict__ w3,
                                              short* __restrict__ o0,
                                              short* __restrict__ o1,
                                              short* __restrict__ o2,
                                              short* __restrict__ o3,
                                              float* __restrict__ ct,
                                              float* __restrict__ st) {
    __shared__ float tile[32][33];
    const int bid = blockIdx.x;
    const int t   = threadIdx.x;

    if (bid < 4096) {
        size_t i = (size_t)bid * 256 + t;
        const float4* p = (const float4*)x + i * 2;
        float4 a = p[0], b = p[1];
        bf16x8 o;
        o[0]=f2b(a.x); o[1]=f2b(a.y); o[2]=f2b(a.z); o[3]=f2b(a.w);
        o[4]=f2b(b.x); o[5]=f2b(b.y); o[6]=f2b(b.z); o[7]=f2b(b.w);
        *((bf16x8*)xb + i) = o;
    } else if (bid < 8192) {
        const int wid = bid - 4096;
        const int z   = wid >> 10;          // 0..3
        const int t2  = wid & 1023;
        const int bx  = (t2 & 31) * 32;
        const int by  = (t2 >> 5) * 32;
        const float* src = z == 0 ? w0 : z == 1 ? w1 : z == 2 ? w2 : w3;
        short*       dst = z == 0 ? o0 : z == 1 ? o1 : z == 2 ? o2 : o3;
        const int tx = t & 31, ty = t >> 5;  // 32 x 8
        #pragma unroll
        for (int i = 0; i < 4; ++i)
            tile[ty * 4 + i][tx] = src[(size_t)(by + ty * 4 + i) * D_DIM + bx + tx];
        __syncthreads();
        #pragma unroll
        for (int i = 0; i < 4; ++i)
            dst[(size_t)(bx + ty * 4 + i) * D_DIM + by + tx] = f2b(tile[tx][ty * 4 + i]);
    } else {
        int i = (bid - 8192) * 256 + t;      // 2048*32 = 65536
        int s = i >> 5, tt = i & 31;
        float inv = (float)pow(10000.0, -(double)(2 * tt) / 64.0);
        float ang = (float)s * inv;
        float sn, cs;
        sincosf(ang, &sn, &cs);
        ct[i] = cs; st[i] = sn;
    }
}

// ---------------- merged QKV GEMM (z = 0:Q, 1:K, 2:V) ----------------
// XCD-owns-A remap (R13-proven). Q/K staged epilogue (bit-exact per R14/R15
// bisect). __launch_bounds__(256,4): cap VGPR at 128 (R16->R17: 137->62 µs).
__global__ __launch_bounds__(256, 4) void gemm_qkv_k(const short* __restrict__ A,
                                                     const short* __restrict__ Wt3,
                                                     short* __restrict__ Qb,
                                                     short* __restrict__ Kb,
                                                     short* __restrict__ Vt,
                                                     const float* __restrict__ ctab,
                                                     const float* __restrict__ stab) {
    const int K = 1024;
    __shared__ __align__(16) short smem[2 * 128 * 64];   // As|Bs; reused for C-stage
    short* As = smem;
    short* Bs = smem + 128 * 64;

    const int z = blockIdx.z;
    const short* BT = Wt3 + (size_t)z * D_DIM * D_DIM;

    const int l = blockIdx.y * 8 + blockIdx.x;   // 0..511
    const int mbase = ((l & 7) * 8 + (l >> 6)) * 128;
    const int nbase = ((l >> 3) & 7) * 128;

    const int t = threadIdx.x;
    const int lane = t & 63;
    const int li = lane & 15;
    const int g  = lane >> 4;
    const int w  = t >> 6;
    const int wr = w >> 1, wc = w & 1;

    f32x4 acc[4][4] = {};

    for (int kt = 0; kt < K / 64; ++kt) {
        const int k0 = kt * 64;
        #pragma unroll
        for (int it = 0; it < 4; ++it) {
            int idx = it * 256 + t;
            int r = idx >> 3, p = idx & 7;
            int c = p ^ (r & 7);
            gld_lds16(A + (size_t)(mbase + r) * K + k0 + c * 8, &As[idx * 8]);
        }
        #pragma unroll
        for (int it = 0; it < 4; ++it) {
            int idx = it * 256 + t;
            int r = idx >> 3, p = idx & 7;
            int c = p ^ (r & 7);
            gld_lds16(BT + (size_t)(nbase + r) * K + k0 + c * 8, &Bs[idx * 8]);
        }
        __syncthreads();

        #pragma unroll
        for (int kk = 0; kk < 2; ++kk) {
            bf16x8 af[4], bfr[4];
            #pragma unroll
            for (int mt = 0; mt < 4; ++mt) {
                int row = wr * 64 + mt * 16 + li;
                int c = (kk * 4 + g) ^ (row & 7);
                af[mt] = *(const bf16x8*)&As[row * 64 + c * 8];
            }
            #pragma unroll
            for (int nt = 0; nt < 4; ++nt) {
                int row = wc * 64 + nt * 16 + li;
                int c = (kk * 4 + g) ^ (row & 7);
                bfr[nt] = *(const bf16x8*)&Bs[row * 64 + c * 8];
            }
            #pragma unroll
            for (int mt = 0; mt < 4; ++mt)
                #pragma unroll
                for (int nt = 0; nt < 4; ++nt)
                    acc[mt][nt] = __builtin_amdgcn_mfma_f32_16x16x32_bf16(
                        af[mt], bfr[nt], acc[mt][nt], 0, 0, 0);
        }
        __syncthreads();
    }

    if (z == 2) {
        // V: stage C^T tile into smem [nloc][mloc] (chunk-XOR), then coalesced rows
        #pragma unroll
        for (int mt = 0; mt < 4; ++mt) {
            #pragma unroll
            for (int nt = 0; nt < 4; ++nt) {
                const int nloc = wc * 64 + nt * 16 + li;
                #pragma unroll
                for (int j = 0; j < 4; ++j) {
                    const int mloc = wr * 64 + mt * 16 + g * 4 + j;
                    smem[nloc * 128 + (((mloc >> 3) ^ (nloc & 7)) << 3) + (mloc & 7)] =
                        f2b(acc[mt][nt][j]);
                }
            }
        }
        __syncthreads();
        const int b = mbase >> 11, s2 = mbase & (S_LEN - 1);
        #pragma unroll
        for (int rr = 0; rr < 8; ++rr) {
            const int row = w * 32 + rr * 4 + (lane >> 4);   // nloc
            const int mc  = lane & 15;
            const int phys = mc ^ (row & 7);
            bf16x8 vrow = *(const bf16x8*)&smem[row * 128 + phys * 8];
            const int n = nbase + row;
            const int h = n >> 6, dk = n & 63;
            *(bf16x8*)&Vt[((size_t)((b * NH + h) * DKD + dk)) * S_LEN + s2 + mc * 8] = vrow;
        }
    } else {
        // Q/K: RoPE in-register, stage C [mloc][nloc] chunk-XOR, coalesced stores
        short* Out = (z == 0) ? Qb : Kb;
        const int s2b = mbase & (S_LEN - 1);
        #pragma unroll
        for (int mt = 0; mt < 4; ++mt) {
            #pragma unroll
            for (int nt = 0; nt < 4; ++nt) {
                const int nloc = wc * 64 + nt * 16 + li;
                const int tt = (nloc & 63) >> 1;
                #pragma unroll
                for (int j = 0; j < 4; ++j) {
                    const int mloc = wr * 64 + mt * 16 + g * 4 + j;
                    const int s2 = s2b + mloc;
                    float v = acc[mt][nt][j];
                    float pv = __shfl_xor(v, 1);
                    float cs = ctab[s2 * 32 + tt];
                    float sn = stab[s2 * 32 + tt];
                    float o = (nloc & 1) ? (pv * sn + v * cs) : (v * cs - pv * sn);
                    if (z == 0) o *= QSCALE;
                    smem[mloc * 128 + (((nloc >> 3) ^ (mloc & 7)) << 3) + (nloc & 7)] = f2b(o);
                }
            }
        }
        __syncthreads();
        const int b = mbase >> 11;
        const int seg = lane >> 3, pos = lane & 7;
        const int half = seg & 1;
        const int h = (nbase >> 6) + half;
        #pragma unroll
        for (int rr = 0; rr < 8; ++rr) {
            const int rloc = w * 32 + rr * 4 + (seg >> 1);
            const int chunk = half * 8 + pos;
            bf16x8 vrow = *(const bf16x8*)&smem[rloc * 128 + ((chunk ^ (rloc & 7)) << 3)];
            *(bf16x8*)&Out[((size_t)((b * NH + h) * S_LEN + s2b + rloc)) * DKD + pos * 8] = vrow;
        }
    }
}

// ---------------- output GEMM: out[M][1024] fp32, XCD-owns-A remap (R13) ----------
__global__ __launch_bounds__(256) void gemm_out_k(const short* __restrict__ A,
                                                  const short* __restrict__ BT,
                                                  float* __restrict__ Cout) {
    const int K = 1024;
    __shared__ short As[128 * 64];
    __shared__ short Bs[128 * 64];

    const int l = blockIdx.y * 8 + blockIdx.x;   // 0..511
    const int mbase = ((l & 7) * 8 + (l >> 6)) * 128;
    const int nbase = ((l >> 3) & 7) * 128;

    const int t = threadIdx.x;
    const int lane = t & 63;
    const int li = lane & 15;
    const int g  = lane >> 4;
    const int w  = t >> 6;
    const int wr = w >> 1, wc = w & 1;

    f32x4 acc[4][4] = {};

    for (int kt = 0; kt < K / 64; ++kt) {
        const int k0 = kt * 64;
        #pragma unroll
        for (int it = 0; it < 4; ++it) {
            int idx = it * 256 + t;
            int r = idx >> 3, p = idx & 7;
            int c = p ^ (r & 7);
            gld_lds16(A + (size_t)(mbase + r) * K + k0 + c * 8, &As[idx * 8]);
        }
        #pragma unroll
        for (int it = 0; it < 4; ++it) {
            int idx = it * 256 + t;
            int r = idx >> 3, p = idx & 7;
            int c = p ^ (r & 7);
            gld_lds16(BT + (size_t)(nbase + r) * K + k0 + c * 8, &Bs[idx * 8]);
        }
        __syncthreads();

        #pragma unroll
        for (int kk = 0; kk < 2; ++kk) {
            bf16x8 af[4], bfr[4];
            #pragma unroll
            for (int mt = 0; mt < 4; ++mt) {
                int row = wr * 64 + mt * 16 + li;
                int c = (kk * 4 + g) ^ (row & 7);
                af[mt] = *(const bf16x8*)&As[row * 64 + c * 8];
            }
            #pragma unroll
            for (int nt = 0; nt < 4; ++nt) {
                int row = wc * 64 + nt * 16 + li;
                int c = (kk * 4 + g) ^ (row & 7);
                bfr[nt] = *(const bf16x8*)&Bs[row * 64 + c * 8];
            }
            #pragma unroll
            for (int mt = 0; mt < 4; ++mt)
                #pragma unroll
                for (int nt = 0; nt < 4; ++nt)
                    acc[mt][nt] = __builtin_amdgcn_mfma_f32_16x16x32_bf16(
                        af[mt], bfr[nt], acc[mt][nt], 0, 0, 0);
        }
        __syncthreads();
    }

    #pragma unroll
    for (int mt = 0; mt < 4; ++mt)
        #pragma unroll
        for (int nt = 0; nt < 4; ++nt) {
            const int n = nbase + wc * 64 + nt * 16 + li;
            #pragma unroll
            for (int j = 0; j < 4; ++j) {
                const int m = mbase + wr * 64 + mt * 16 + g * 4 + j;
                Cout[(size_t)m * D_DIM + n] = acc[mt][nt][j];
            }
        }
}

// ---------------- flash attention, swapped-QK 32x32, no max (R12 attn verbatim) ---
__global__ __launch_bounds__(256, 4) void attn_k(const short* __restrict__ Qb,
                                                 const short* __restrict__ Kb,
                                                 const short* __restrict__ Vt,
                                                 short* __restrict__ Ao) {
    __shared__ short Ks[2][64 * 64];
    __shared__ short Vs[2][64 * 64];

    const int braw = blockIdx.y * 16 + blockIdx.x;   // nwg=1024
    const int tile = (braw & 7) * 128 + (braw >> 3);
    const int bxs = tile & 15, bh = tile >> 4;       // blocks sharing bh -> same XCD

    const int t = threadIdx.x;
    const int lane = t & 63;
    const int ql = lane & 31;
    const int hi = lane >> 5;
    const int w  = t >> 6;
    const int q0 = bxs * 128;

    // Q fragments (B-operand): lane holds Q[q=ql][k = kb*16 + hi*8 + i]
    bf16x8 aq[4];
    {
        const short* qp = Qb + ((size_t)bh * S_LEN + q0 + w * 32 + ql) * DKD;
        #pragma unroll
        for (int kb = 0; kb < 4; ++kb)
            aq[kb] = *(const bf16x8*)(qp + kb * 16 + hi * 8);
    }

    f32x16 oacc[2] = {};
    float lsum = 0.f;

    auto stageKV = [&](int bb, int kt) {
        const int kb = kt * 64;
        #pragma unroll
        for (int it = 0; it < 2; ++it) {
            int idx = it * 256 + t;
            int r = idx >> 3, p = idx & 7;
            int c = p ^ (r & 7);
            gld_lds16(Kb + ((size_t)bh * S_LEN + kb + r) * DKD + c * 8, &Ks[bb][idx * 8]);
        }
        #pragma unroll
        for (int it = 0; it < 2; ++it) {
            int idx = it * 256 + t;
            int r = idx >> 3, p = idx & 7;
            int c = p ^ (r & 7);
            gld_lds16(Vt + ((size_t)bh * DKD + r) * S_LEN + kb + c * 8, &Vs[bb][idx * 8]);
        }
    };

    stageKV(0, 0);
    int buf = 0;
    for (int kt = 0; kt < S_LEN / 64; ++kt) {
        __syncthreads();                                   // staged tile ready
        if (kt + 1 < S_LEN / 64) stageKV(buf ^ 1, kt + 1); // prefetch next

        const short* KsB = Ks[buf];
        const short* VsB = Vs[buf];

        // S^T = K·Q^T   (already in exp2 domain via QSCALE)
        f32x16 s0 = {}, s1 = {};
        #pragma unroll
        for (int kb = 0; kb < 4; ++kb) {
            const int ch = ((kb * 2 + hi) ^ (ql & 7)) * 8;
            bf16x8 k0 = *(const bf16x8*)&KsB[ql * 64 + ch];
            bf16x8 k1 = *(const bf16x8*)&KsB[(ql + 32) * 64 + ch];
            s0 = __builtin_amdgcn_mfma_f32_32x32x16_bf16(k0, aq[kb], s0, 0, 0, 0);
            s1 = __builtin_amdgcn_mfma_f32_32x32x16_bf16(k1, aq[kb], s1, 0, 0, 0);
        }

        // P = exp2(S) directly (no max subtraction); accumulate row sum
        float rs0 = 0.f, rs1 = 0.f;
        #pragma unroll
        for (int r = 0; r < 16; ++r) {
            s0[r] = fast_exp2(s0[r]); rs0 += s0[r];
            s1[r] = fast_exp2(s1[r]); rs1 += s1[r];
        }
        float rs = rs0 + rs1;
        rs += __shfl_xor(rs, 32);
        lsum += rs;

        // pack P into PV B-fragments: cvt_pk pairs + permlane32_swap (T12)
        bf16x8 pb[4];
        #pragma unroll
        for (int kb2 = 0; kb2 < 2; ++kb2) {
            uint32_t A0 = cvtpk(s0[kb2 * 8 + 0], s0[kb2 * 8 + 1]);
            uint32_t A1 = cvtpk(s0[kb2 * 8 + 2], s0[kb2 * 8 + 3]);
            uint32_t A2 = cvtpk(s0[kb2 * 8 + 4], s0[kb2 * 8 + 5]);
            uint32_t A3 = cvtpk(s0[kb2 * 8 + 6], s0[kb2 * 8 + 7]);
            pl32swap(A0, A2); pl32swap(A1, A3);
            union { uint32_t u[4]; bf16x8 v; } pk;
            pk.u[0] = A0; pk.u[1] = A1; pk.u[2] = A2; pk.u[3] = A3;
            pb[kb2] = pk.v;

            uint32_t B0 = cvtpk(s1[kb2 * 8 + 0], s1[kb2 * 8 + 1]);
            uint32_t B1 = cvtpk(s1[kb2 * 8 + 2], s1[kb2 * 8 + 3]);
            uint32_t B2 = cvtpk(s1[kb2 * 8 + 4], s1[kb2 * 8 + 5]);
            uint32_t B3 = cvtpk(s1[kb2 * 8 + 6], s1[kb2 * 8 + 7]);
            pl32swap(B0, B2); pl32swap(B1, B3);
            union { uint32_t u[4]; bf16x8 v; } pk2;
            pk2.u[0] = B0; pk2.u[1] = B1; pk2.u[2] = B2; pk2.u[3] = B3;
            pb[2 + kb2] = pk2.v;
        }

        // O^T += V^T · P^T
        #pragma unroll
        for (int ds = 0; ds < 2; ++ds)
            #pragma unroll
            for (int kb = 0; kb < 4; ++kb) {
                const int ch = ((kb * 2 + hi) ^ (ql & 7)) * 8;
                bf16x8 vf = *(const bf16x8*)&VsB[(ds * 32 + ql) * 64 + ch];
                oacc[ds] = __builtin_amdgcn_mfma_f32_32x32x16_bf16(vf, pb[kb], oacc[ds], 0, 0, 0);
            }
        buf ^= 1;
    }

    // epilogue: lane owns q = q0 + w*32 + ql entirely
    const float inv = 1.0f / lsum;
    const int b = bh >> 4, h = bh & 15;
    short* op = Ao + ((size_t)(b * S_LEN + q0 + w * 32 + ql)) * D_DIM + h * DKD;
    #pragma unroll
    for (int ds = 0; ds < 2; ++ds)
        #pragma unroll
        for (int r4 = 0; r4 < 4; ++r4) {
            uint2 pk;
            pk.x = cvtpk(oacc[ds][r4 * 4 + 0] * inv, oacc[ds][r4 * 4 + 1] * inv);
            pk.y = cvtpk(oacc[ds][r4 * 4 + 2] * inv, oacc[ds][r4 * 4 + 3] * inv);
            *(uint2*)(op + ds * 32 + r4 * 8 + hi * 4) = pk;
        }
}

// ---------------- launch ----------------
extern "C" void kernel_launch(void* const* d_in, const int* in_sizes, int n_in,
                              void* d_out, int out_size, void* d_ws, size_t ws_size,
                              hipStream_t stream) {
    const float* x  = (const float*)d_in[0];
    const float* Wq = (const float*)d_in[2];
    const float* Wk = (const float*)d_in[3];
    const float* Wv = (const float*)d_in[4];
    const float* Wo = (const float*)d_in[5];

    char* ws = (char*)d_ws;
    short* xb  = (short*)(ws);                         // 16 MB
    short* Wqt = (short*)(ws + (size_t)(16 << 20));    // 2 MB each; Wq/Wk/Wv contiguous
    short* Wkt = (short*)(ws + (size_t)(18 << 20));
    short* Wvt = (short*)(ws + (size_t)(20 << 20));
    short* Wot = (short*)(ws + (size_t)(22 << 20));
    short* Qb  = (short*)(ws + (size_t)(24 << 20));    // 16 MB [BH][S][DK]
    short* Kb  = (short*)(ws + (size_t)(40 << 20));    // 16 MB
    short* Vt  = (short*)(ws + (size_t)(56 << 20));    // 16 MB [BH][DK][S]
    short* Ao  = (short*)(ws + (size_t)(72 << 20));    // 16 MB [B][S][D]
    float* ctab = (float*)(ws + (size_t)(88 << 20));   // 256 KB
    float* stab = (float*)(ws + (size_t)(88 << 20) + (1 << 18));

    prep_k<<<8448, 256, 0, stream>>>(x, xb, Wq, Wk, Wv, Wo, Wqt, Wkt, Wvt, Wot, ctab, stab);

    gemm_qkv_k<<<dim3(8, 64, 3), 256, 0, stream>>>(xb, Wqt, Qb, Kb, Vt, ctab, stab);

    attn_k<<<dim3(16, 64), 256, 0, stream>>>(Qb, Kb, Vt, Ao);

    gemm_out_k<<<dim3(8, 64), 256, 0, stream>>>(Ao, Wot, (float*)d_out);
}